// Round 1
// baseline (1292.742 us; speedup 1.0000x reference)
//
#include <hip/hip_runtime.h>

#define EMB 300
#define NCH 75          // EMB / 4 (float4 chunks per row; exact, no tail)
#define NT 12           // num tasks
#define NG 16384        // num graphs
#define NPL 4           // nodes per lane
#define THREADS 256     // 4 waves per block

// Kernel 1: fused per-node projection (x_i . W_t for 12 t's) + sorted-segment
// reduction into per-graph accumulators via wave segmented scan + atomics.
__global__ __launch_bounds__(THREADS) void pool_proj_kernel(
    const float* __restrict__ x, const int* __restrict__ batch,
    const float* __restrict__ W, float* __restrict__ acc,
    float* __restrict__ cnt, int n)
{
    const int lane = threadIdx.x & 63;
    const int wave = threadIdx.x >> 6;
    // Wave covers 4 consecutive 64-node windows: nodes [wbase, wbase+256)
    const int wbase = (blockIdx.x * (THREADS / 64) + wave) * (64 * NPL);

    int node[NPL];
    int g[NPL];
    bool valid[NPL];
#pragma unroll
    for (int k = 0; k < NPL; ++k) {
        int nk = wbase + k * 64 + lane;
        valid[k] = (nk < n);
        node[k] = valid[k] ? nk : 0;
        // invalid lanes get a unique sentinel graph id -> singleton runs,
        // excluded from atomics (>= NG) and never merge with valid runs.
        g[k] = valid[k] ? batch[node[k]] : (0x40000000 + lane);
    }

    float accv[NPL][NT];
#pragma unroll
    for (int k = 0; k < NPL; ++k)
#pragma unroll
        for (int t = 0; t < NT; ++t) accv[k][t] = 0.0f;

    const float4* __restrict__ xv = (const float4*)x;
    const float4* __restrict__ wv = (const float4*)W;

    // Per-lane row base indices (float4 units)
    size_t xbase[NPL];
#pragma unroll
    for (int k = 0; k < NPL; ++k) xbase[k] = (size_t)node[k] * NCH;

    for (int c = 0; c < NCH; ++c) {
        // W chunk: wave-uniform addresses -> broadcast/scalar loads, L1-resident
        float4 w[NT];
#pragma unroll
        for (int t = 0; t < NT; ++t) w[t] = wv[t * NCH + c];
#pragma unroll
        for (int k = 0; k < NPL; ++k) {
            float4 xk = xv[xbase[k] + c];
#pragma unroll
            for (int t = 0; t < NT; ++t) {
                accv[k][t] = fmaf(xk.x, w[t].x,
                             fmaf(xk.y, w[t].y,
                             fmaf(xk.z, w[t].z,
                             fmaf(xk.w, w[t].w, accv[k][t]))));
            }
        }
    }

    // Per 64-node window: segmented inclusive scan over run-encoded sorted ids,
    // tail lane of each run commits the run total with one atomicAdd per task.
#pragma unroll
    for (int k = 0; k < NPL; ++k) {
        int gk = g[k];
#pragma unroll
        for (int off = 1; off < 64; off <<= 1) {
            int gu = __shfl_up(gk, off);
            bool add = (lane >= off) && (gu == gk);
#pragma unroll
            for (int t = 0; t < NT; ++t) {
                float vu = __shfl_up(accv[k][t], off);
                if (add) accv[k][t] += vu;
            }
        }
        int gnext = __shfl_down(gk, 1);
        int gprev = __shfl_up(gk, 1);
        bool tail = (lane == 63) || (gnext != gk);
        bool head = (lane == 0) || (gprev != gk);
        unsigned long long heads = __ballot(head);
        if (tail && gk < NG) {
            // run length from head-flag ballot: highest head bit at/below me
            unsigned long long below = heads & (~0ull >> (63 - lane));
            int run_start = 63 - __builtin_clzll(below);
            float count = (float)(lane - run_start + 1);
#pragma unroll
            for (int t = 0; t < NT; ++t)
                atomicAdd(&acc[gk * NT + t], accv[k][t]);
            atomicAdd(&cnt[gk], count);
        }
    }
}

// Kernel 2: out[g,t] = acc[g,t] / max(cnt[g],1) + b[t]
__global__ __launch_bounds__(256) void finalize_kernel(
    const float* __restrict__ acc, const float* __restrict__ cnt,
    const float* __restrict__ b, float* __restrict__ out)
{
    int idx = blockIdx.x * 256 + threadIdx.x;
    if (idx >= NG * NT) return;
    int gi = idx / NT;
    int t = idx - gi * NT;
    out[idx] = acc[idx] / fmaxf(cnt[gi], 1.0f) + b[t];
}

extern "C" void kernel_launch(void* const* d_in, const int* in_sizes, int n_in,
                              void* d_out, int out_size, void* d_ws, size_t ws_size,
                              hipStream_t stream) {
    const float* x     = (const float*)d_in[0];
    const int*   batch = (const int*)d_in[1];   // harness delivers integer inputs as int32
    const float* W     = (const float*)d_in[2];
    const float* b     = (const float*)d_in[3];
    float* out = (float*)d_out;

    float* acc = (float*)d_ws;            // NG*NT accumulators
    float* cnt = acc + (size_t)NG * NT;   // NG counts

    const int n = in_sizes[1];            // 500000 nodes

    hipMemsetAsync(d_ws, 0, ((size_t)NG * NT + NG) * sizeof(float), stream);

    const int nodes_per_block = (THREADS / 64) * 64 * NPL;  // 1024
    const int nblocks = (n + nodes_per_block - 1) / nodes_per_block;
    pool_proj_kernel<<<nblocks, THREADS, 0, stream>>>(x, batch, W, acc, cnt, n);

    finalize_kernel<<<(NG * NT + 255) / 256, 256, 0, stream>>>(acc, cnt, b, out);
}

// Round 2
// 923.345 us; speedup vs baseline: 1.4001x; 1.4001x over previous
//
#include <hip/hip_runtime.h>

#define NT 12             // num tasks
#define NG 16384          // num graphs
#define NCH 75            // float4 chunks per 300-float row
#define ROWS 64           // rows per block tile
#define THREADS 256       // 4 waves
#define STAGE_ITERS 19    // ceil(ROWS*NCH / THREADS) = ceil(4800/256)

// Stage 64 contiguous rows into LDS with coalesced loads (corner-turn), then
// lane=row computes 12-task projection with wave-uniform (scalar) W loads;
// per-wave segmented scan over sorted graph ids -> one atomicAdd per run.
__global__ __launch_bounds__(THREADS) void pool_proj_kernel(
    const float4* __restrict__ xv, const int* __restrict__ batch,
    const float4* __restrict__ wv, float* __restrict__ acc,
    float* __restrict__ cnt, int n)
{
    extern __shared__ float4 tile[];   // ROWS*NCH = 4800 float4s = 76.8 KB

    const int tid = threadIdx.x;
    const int lane = tid & 63;
    const long long base_row = (long long)blockIdx.x * ROWS;
    const long long base_f4 = base_row * NCH;
    const long long total_f4 = (long long)n * NCH;

    // ---- stage: one contiguous 76.8 KB span, stride-1 LDS writes ----
#pragma unroll
    for (int i = 0; i < STAGE_ITERS; ++i) {
        int q = tid + i * THREADS;
        if (q < ROWS * NCH) {
            long long gq = base_f4 + q;
            float4 v = make_float4(0.f, 0.f, 0.f, 0.f);
            if (gq < total_f4) v = xv[gq];
            tile[q] = v;
        }
    }
    __syncthreads();

    // ---- compute: wave w handles chunk range, lane = row ----
    const int wvid = __builtin_amdgcn_readfirstlane(tid >> 6);
    const int cbeg = wvid * 19;
    const int cend = (wvid == 3) ? NCH : (cbeg + 19);
    const int r = lane;

    float a[NT];
#pragma unroll
    for (int t = 0; t < NT; ++t) a[t] = 0.0f;

    for (int c = cbeg; c < cend; ++c) {
        float4 xk = tile[r * NCH + c];       // bank-quad (3r+c)%8: conflict-free
        float4 w[NT];
#pragma unroll
        for (int t = 0; t < NT; ++t) w[t] = wv[t * NCH + c];  // wave-uniform -> s_load
#pragma unroll
        for (int t = 0; t < NT; ++t) {
            a[t] = fmaf(xk.x, w[t].x,
                   fmaf(xk.y, w[t].y,
                   fmaf(xk.z, w[t].z,
                   fmaf(xk.w, w[t].w, a[t]))));
        }
    }

    // ---- per-wave segmented scan over sorted graph ids ----
    long long grow = base_row + lane;
    int g = (grow < n) ? batch[grow] : (0x40000000 + lane);  // unique sentinel

#pragma unroll
    for (int off = 1; off < 64; off <<= 1) {
        int gu = __shfl_up(g, off);
        bool add = (lane >= off) && (gu == g);
#pragma unroll
        for (int t = 0; t < NT; ++t) {
            float vu = __shfl_up(a[t], off);
            if (add) a[t] += vu;
        }
    }
    int gnext = __shfl_down(g, 1);
    int gprev = __shfl_up(g, 1);
    bool tail = (lane == 63) || (gnext != g);
    bool head = (lane == 0) || (gprev != g);
    unsigned long long heads = __ballot(head);
    if (tail && g < NG) {
#pragma unroll
        for (int t = 0; t < NT; ++t)
            atomicAdd(&acc[g * NT + t], a[t]);
        if (wvid == 0) {  // counts added once per window, not per wave
            unsigned long long below = heads & (~0ull >> (63 - lane));
            int run_start = 63 - __builtin_clzll(below);
            atomicAdd(&cnt[g], (float)(lane - run_start + 1));
        }
    }
}

// out[g,t] = acc[g,t] / max(cnt[g],1) + b[t]
__global__ __launch_bounds__(256) void finalize_kernel(
    const float* __restrict__ acc, const float* __restrict__ cnt,
    const float* __restrict__ b, float* __restrict__ out)
{
    int idx = blockIdx.x * 256 + threadIdx.x;
    if (idx >= NG * NT) return;
    int gi = idx / NT;
    int t = idx - gi * NT;
    out[idx] = acc[idx] / fmaxf(cnt[gi], 1.0f) + b[t];
}

extern "C" void kernel_launch(void* const* d_in, const int* in_sizes, int n_in,
                              void* d_out, int out_size, void* d_ws, size_t ws_size,
                              hipStream_t stream) {
    const float* x     = (const float*)d_in[0];
    const int*   batch = (const int*)d_in[1];
    const float* W     = (const float*)d_in[2];
    const float* b     = (const float*)d_in[3];
    float* out = (float*)d_out;

    float* acc = (float*)d_ws;
    float* cnt = acc + (size_t)NG * NT;

    const int n = in_sizes[1];  // 500000 nodes

    hipMemsetAsync(d_ws, 0, ((size_t)NG * NT + NG) * sizeof(float), stream);

    const int nblocks = (n + ROWS - 1) / ROWS;   // 7813
    const size_t lds_bytes = (size_t)ROWS * NCH * sizeof(float4);  // 76800
    pool_proj_kernel<<<nblocks, THREADS, lds_bytes, stream>>>(
        (const float4*)x, batch, (const float4*)W, acc, cnt, n);

    finalize_kernel<<<(NG * NT + 255) / 256, 256, 0, stream>>>(acc, cnt, b, out);
}

// Round 3
// 916.951 us; speedup vs baseline: 1.4098x; 1.0070x over previous
//
#include <hip/hip_runtime.h>
#include <stdint.h>

#define NT 12             // num tasks
#define NG 16384          // num graphs
#define NCH 75            // float4 chunks per 300-float row
#define ROWS 32           // rows per tile (500000 = 32 * 15625 exactly)
#define THREADS 128       // 2 waves
#define TILE_F4 (ROWS * NCH)      // 2400 float4 = 38.4 KB
#define FULL_ITERS 18             // 18*128 = 2304
#define TAIL_ACTIVE (TILE_F4 - FULL_ITERS * THREADS)   // 96

typedef const __attribute__((address_space(1))) uint32_t gas_u32;
typedef __attribute__((address_space(3))) uint32_t las_u32;

// Stage 32 contiguous rows into LDS via async global_load_lds (width=16,
// no VGPR round-trip), then lane covers (row, chunk-quarter): r=lane&31,
// h=2*wave+(lane>>5). Fold halves, 5-step segmented scan over sorted graph
// ids per 32-row window, one atomicAdd per run per task.
__global__ __launch_bounds__(THREADS) void pool_proj_kernel(
    const float4* __restrict__ xv, const int* __restrict__ batch,
    const float4* __restrict__ wv, float* __restrict__ acc,
    float* __restrict__ cnt, int n)
{
    extern __shared__ float4 tile[];   // TILE_F4 float4s

    const int tid = threadIdx.x;
    const int lane = tid & 63;
    const int wvid = tid >> 6;
    const long long base_row = (long long)blockIdx.x * ROWS;
    const long long base_f4 = base_row * NCH;
    const long long total_f4 = (long long)n * NCH;

    if (base_f4 + TILE_F4 <= total_f4) {
        // ---- async stage: LDS dest = wave-uniform base + lane*16 ----
        const float4* gsrc = xv + base_f4;
#pragma unroll
        for (int i = 0; i < FULL_ITERS; ++i) {
            const int seg = i * THREADS + 64 * wvid;   // wave-uniform
            __builtin_amdgcn_global_load_lds(
                (gas_u32*)(gsrc + seg + lane),
                (las_u32*)(tile + seg), 16, 0, 0);
        }
        if (tid < TAIL_ACTIVE) {                        // wave0 full, wave1 half
            const int seg = FULL_ITERS * THREADS + 64 * wvid;
            __builtin_amdgcn_global_load_lds(
                (gas_u32*)(gsrc + seg + lane),
                (las_u32*)(tile + seg), 16, 0, 0);
        }
    } else {
        // guarded fallback (only if n % 32 != 0 — not hit for n=500000)
        for (int q = tid; q < TILE_F4; q += THREADS) {
            long long gq = base_f4 + q;
            tile[q] = (gq < total_f4) ? xv[gq] : make_float4(0.f, 0.f, 0.f, 0.f);
        }
    }
    __syncthreads();

    // ---- compute: r = row, h = chunk-quarter ----
    const int r = lane & 31;
    const int h = (wvid << 1) | (lane >> 5);   // 0..3
    const int cbase = h * 19;                  // quarters: 19,19,19,18 chunks

    float a[NT];
#pragma unroll
    for (int t = 0; t < NT; ++t) a[t] = 0.0f;

#pragma unroll
    for (int j = 0; j < 19; ++j) {
        const int c = cbase + j;
        if (c < NCH) {
            float4 xk = tile[r * NCH + c];
#pragma unroll
            for (int t = 0; t < NT; ++t) {
                float4 w = wv[t * NCH + c];    // L1-resident (14.4 KB)
                a[t] = fmaf(xk.x, w.x,
                       fmaf(xk.y, w.y,
                       fmaf(xk.z, w.z,
                       fmaf(xk.w, w.w, a[t]))));
            }
        }
    }

    // ---- fold chunk-halves: lanes 0..31 get full row partials for this wave ----
#pragma unroll
    for (int t = 0; t < NT; ++t) a[t] += __shfl_down(a[t], 32);

    long long grow = base_row + r;
    int g = (lane < 32 && grow < n) ? batch[grow] : (0x40000000 + lane);

    // ---- segmented inclusive scan within the 32-row window ----
#pragma unroll
    for (int off = 1; off < 32; off <<= 1) {
        int gu = __shfl_up(g, off);
        bool add = (r >= off) && (gu == g);
#pragma unroll
        for (int t = 0; t < NT; ++t) {
            float vu = __shfl_up(a[t], off);
            if (add) a[t] += vu;
        }
    }
    int gnext = __shfl_down(g, 1);
    int gprev = __shfl_up(g, 1);
    bool tail = (r == 31) || (gnext != g);
    bool head = (r == 0) || (gprev != g);
    unsigned long long heads = __ballot(head);

    if (lane < 32 && tail && g < NG) {
#pragma unroll
        for (int t = 0; t < NT; ++t)
            atomicAdd(&acc[g * NT + t], a[t]);
        if (wvid == 0) {   // counts once per window
            unsigned long long below = heads & (~0ull >> (63 - lane));
            int run_start = 63 - __builtin_clzll(below);
            atomicAdd(&cnt[g], (float)(lane - run_start + 1));
        }
    }
}

// out[g,t] = acc[g,t] / max(cnt[g],1) + b[t]
__global__ __launch_bounds__(256) void finalize_kernel(
    const float* __restrict__ acc, const float* __restrict__ cnt,
    const float* __restrict__ b, float* __restrict__ out)
{
    int idx = blockIdx.x * 256 + threadIdx.x;
    if (idx >= NG * NT) return;
    int gi = idx / NT;
    int t = idx - gi * NT;
    out[idx] = acc[idx] / fmaxf(cnt[gi], 1.0f) + b[t];
}

extern "C" void kernel_launch(void* const* d_in, const int* in_sizes, int n_in,
                              void* d_out, int out_size, void* d_ws, size_t ws_size,
                              hipStream_t stream) {
    const float* x     = (const float*)d_in[0];
    const int*   batch = (const int*)d_in[1];
    const float* W     = (const float*)d_in[2];
    const float* b     = (const float*)d_in[3];
    float* out = (float*)d_out;

    float* acc = (float*)d_ws;
    float* cnt = acc + (size_t)NG * NT;

    const int n = in_sizes[1];  // 500000 nodes

    hipMemsetAsync(d_ws, 0, ((size_t)NG * NT + NG) * sizeof(float), stream);

    const int nblocks = (n + ROWS - 1) / ROWS;   // 15625
    const size_t lds_bytes = (size_t)TILE_F4 * sizeof(float4);  // 38400
    pool_proj_kernel<<<nblocks, THREADS, lds_bytes, stream>>>(
        (const float4*)x, batch, (const float4*)W, acc, cnt, n);

    finalize_kernel<<<(NG * NT + 255) / 256, 256, 0, stream>>>(acc, cnt, b, out);
}